// Round 14
// baseline (615.524 us; speedup 1.0000x reference)
//
#include <hip/hip_runtime.h>
#include <math.h>

#define SD 7
#define HID 64
#define NITER 10

typedef float f16s __attribute__((ext_vector_type(16)));
typedef float f8s  __attribute__((ext_vector_type(8)));
typedef float f4   __attribute__((ext_vector_type(4)));
typedef float f2   __attribute__((ext_vector_type(2)));

#define REP4(M)  M(0) M(1) M(2) M(3)
#define REP7(M)  M(0) M(1) M(2) M(3) M(4) M(5) M(6)
#define REP15(M) M(1) M(2) M(3) M(4) M(5) M(6) M(7) M(8) M(9) M(10) M(11) M(12) M(13) M(14) M(15)
#define REP16(M) M(0) M(1) M(2) M(3) M(4) M(5) M(6) M(7) M(8) M(9) M(10) M(11) M(12) M(13) M(14) M(15)
#define AP8(M, ...) M(0, __VA_ARGS__) M(1, __VA_ARGS__) M(2, __VA_ARGS__) M(3, __VA_ARGS__) \
    M(4, __VA_ARGS__) M(5, __VA_ARGS__) M(6, __VA_ARGS__) M(7, __VA_ARGS__)

// ---- SMEM loads (r4/r11-proven): uniform weights -> SGPRs, volatile => no hoist ----
#define SLOAD4(d0, d1, d2, d3, p, o0, o1, o2, o3) \
    asm volatile("s_load_dwordx16 %0, %4, %5\n\t" \
                 "s_load_dwordx16 %1, %4, %6\n\t" \
                 "s_load_dwordx16 %2, %4, %7\n\t" \
                 "s_load_dwordx16 %3, %4, %8\n\t" \
                 "s_waitcnt lgkmcnt(0)" \
                 : "=&s"(d0), "=&s"(d1), "=&s"(d2), "=&s"(d3) \
                 : "s"(p), "i"(o0), "i"(o1), "i"(o2), "i"(o3));

#define SLD16(d, obytes, p) \
    asm volatile("s_load_dwordx16 %0, %1, %2\n\t" \
                 "s_waitcnt lgkmcnt(0)" \
                 : "=&s"(d) : "s"(p), "i"(obytes));

#define SLOADX8(d0, p) \
    asm volatile("s_load_dwordx8 %0, %1, 0\n\t" \
                 "s_waitcnt lgkmcnt(0)" \
                 : "=&s"(d0) : "s"(p));

// ---- LDS uniform batched read (r10/r11-proven): 4 x b128, wait inside ----
#define LDS4U(wa, wb, wc, wd, ADDR) \
    asm volatile("ds_read_b128 %0, %4 offset:0\n\t" \
                 "ds_read_b128 %1, %4 offset:16\n\t" \
                 "ds_read_b128 %2, %4 offset:32\n\t" \
                 "ds_read_b128 %3, %4 offset:48\n\t" \
                 "s_waitcnt lgkmcnt(0)" \
                 : "=&v"(wa), "=&v"(wb), "=&v"(wc), "=&v"(wd) : "v"(ADDR));

// ---- pk helpers: even-aligned pair subviews ----
#define PKW(W, e)   __builtin_shufflevector((W), (W), 2*(e), 2*(e)+1)
#define SHF2(V, h_) __builtin_shufflevector((V), (V), 2*(h_), 2*(h_)+1)

#define PKFMA_ACC(acc, ws, mv) \
    asm("v_pk_fma_f32 %0, %1, %2, %0" : "+v"(acc) : "s"(ws), "v"(mv));
#define PKMUL_NEW(dst, ws, mv) \
    asm("v_pk_mul_f32 %0, %1, %2" : "=v"(dst) : "s"(ws), "v"(mv));
#define PKADD_S(acc, ws) \
    asm("v_pk_add_f32 %0, %1, %0" : "+v"(acc) : "s"(ws));
#define PKFMA_GL(g, tv, lss, lbv) \
    asm("v_pk_fma_f32 %0, %1, %2, %3" : "=v"(g) : "v"(tv), "s"(lss), "v"(lbv));

#define PKROW_E(e, arr, base, m2v, W) PKFMA_ACC((arr)[(base)+(e)], PKW(W, e), m2v)
#define PKROW(arr, m2v, wa, wb, wc, wd) \
    AP8(PKROW_E, arr, 0,  m2v, wa) AP8(PKROW_E, arr, 8,  m2v, wb) \
    AP8(PKROW_E, arr, 16, m2v, wc) AP8(PKROW_E, arr, 24, m2v, wd)

#define PKMUL_E(e, arr, base, m2v, W) PKMUL_NEW((arr)[(base)+(e)], PKW(W, e), m2v)
#define PKADD_E(e, arr, base, W) PKADD_S((arr)[(base)+(e)], PKW(W, e))

// out-matmul: acc2 += xe2[pair] * owT-pair (weights from SGPRs)
#define OPK_E(e, acc, base, W) PKFMA_ACC(acc, PKW(W, e), xe2[(base)+(e)])

__global__ void transpose_ow_kernel(const float* __restrict__ ow,
                                    float* __restrict__ owt) {
    int t = threadIdx.x;
    if (t < HID * SD) owt[(t % SD) * HID + (t / SD)] = ow[t];   // owT[i][j]
}

__global__ __launch_bounds__(256) __attribute__((amdgpu_waves_per_eu(3, 3)))
void strange_loop_kernel(const float* __restrict__ s7,
                         const float* __restrict__ w0,
                         const float* __restrict__ b0,
                         const float* __restrict__ lns,
                         const float* __restrict__ lnb,
                         const float* __restrict__ owt,
                         const float* __restrict__ ob,
                         float* __restrict__ out_mu,
                         float* __restrict__ out_cv,
                         int Bn)
{
    __shared__ __align__(16) float lnp[HID];     // lnb staged in LDS (VGPR-pair source)
    const int tid = threadIdx.x;
    if (tid < HID) lnp[tid] = lnb[tid];
    __syncthreads();

    const unsigned alnb = (unsigned)(size_t)(&lnp[0]);
    const unsigned aln0 = alnb, aln1 = alnb + 64, aln2 = alnb + 128, aln3 = alnb + 192;

    int row = blockIdx.x * blockDim.x + tid;
    if (row >= Bn) row = Bn - 1;   // clamp: uniform control flow, dup write benign

    float s[SD];
#define LD_S(k) s[k] = s7[(size_t)row * SD + (k)];
    REP7(LD_S)

    f8s obv;
    SLOADX8(obv, ob)

    float mu[SD];
#define INITMU(i) mu[i] = 0.37796447300922720f;   // 1/sqrt(7)
    REP7(INITMU)
    float conv = 0.0f;

#pragma unroll 1
    for (int it = 0; it < NITER; ++it) {
        // ---- fc0 fully recomputed, packed:
        //      xe2 = (sum_k s[k]*W0[7+k]) + b0 + sum_k mu[k]*W0[k]  ----
        f2 xe2[32];
        { // s-row k=0 initializes (pk_mul)
          f16s wa, wb, wc, wd;
          SLOAD4(wa, wb, wc, wd, w0, 7*256, 7*256+64, 7*256+128, 7*256+192)
          f2 m2 = {s[0], s[0]};
          AP8(PKMUL_E, xe2, 0,  m2, wa) AP8(PKMUL_E, xe2, 8,  m2, wb)
          AP8(PKMUL_E, xe2, 16, m2, wc) AP8(PKMUL_E, xe2, 24, m2, wd)
        }
#define SRK(k) { f16s wa, wb, wc, wd; \
        SLOAD4(wa, wb, wc, wd, w0, (7+(k))*256, (7+(k))*256+64, (7+(k))*256+128, (7+(k))*256+192) \
        f2 m2 = {s[k], s[k]}; \
        PKROW(xe2, m2, wa, wb, wc, wd) }
        SRK(1) SRK(2) SRK(3) SRK(4) SRK(5) SRK(6)
        { // + b0 (SGPR pairs)
          f16s ba, bb, bc, bd;
          SLOAD4(ba, bb, bc, bd, b0, 0, 64, 128, 192)
          AP8(PKADD_E, xe2, 0,  ba) AP8(PKADD_E, xe2, 8,  bb)
          AP8(PKADD_E, xe2, 16, bc) AP8(PKADD_E, xe2, 24, bd)
        }
#define MUK(k) { f16s wa, wb, wc, wd; \
        SLOAD4(wa, wb, wc, wd, w0, (k)*256, (k)*256+64, (k)*256+128, (k)*256+192) \
        f2 m2 = {mu[k], mu[k]}; \
        PKROW(xe2, m2, wa, wb, wc, wd) }
        MUK(0) MUK(1) MUK(2) MUK(3) MUK(4) MUK(5) MUK(6)

        // ---- LayerNorm (r7/r11-proven packed two-pass) ----
        f2 P01 = xe2[0], P23 = xe2[1];
#define SACE(q) P01 += xe2[2*(q)]; P23 += xe2[2*(q)+1];
        REP15(SACE)
        float mean = ((P01.x + P01.y) + (P23.x + P23.y)) * (1.0f / HID);

        f2 V01 = {0.f, 0.f}, V23 = {0.f, 0.f};
        {
            f2 mn2 = {mean, mean};
#define VACE(q) { f2 a0 = xe2[2*(q)] - mn2; f2 a1 = xe2[2*(q)+1] - mn2; \
            V01 = __builtin_elementwise_fma(a0, a0, V01); \
            V23 = __builtin_elementwise_fma(a1, a1, V23); \
            xe2[2*(q)] = a0; xe2[2*(q)+1] = a1; }
            REP16(VACE)
        }
        float var  = ((V01.x + V01.y) + (V23.x + V23.y)) * (1.0f / HID);
        float rstd = 1.0f / sqrtf(var + 1e-6f);

        // ---- scale/shift + GELU (r11-verbatim) ----
        {
            const f2 rs2 = {rstd, rstd};
            const f2 kB2 = {0.044715f, 0.044715f};
            const f2 kC2 = {-1.5957691216057308f, -1.5957691216057308f};
#define GEL1(p, lss, lbv) { \
            f2 t = xe2[p] * rs2; \
            f2 g; PKFMA_GL(g, t, lss, lbv) \
            f2 g2 = g * g; f2 g3 = g2 * g; \
            f2 z = __builtin_elementwise_fma(kB2, g3, g) * kC2; \
            float e0 = __expf(z.x), e1 = __expf(z.y); \
            xe2[p].x = __fdividef(g.x, 1.0f + e0); \
            xe2[p].y = __fdividef(g.y, 1.0f + e1); }
#define GELH(h, AH) { f16s lsg; SLD16(lsg, (h)*64, lns) \
            f4 L0, L1, L2, L3; LDS4U(L0, L1, L2, L3, AH) \
            GEL1(8*(h)+0, PKW(lsg,0), SHF2(L0,0)) \
            GEL1(8*(h)+1, PKW(lsg,1), SHF2(L0,1)) \
            GEL1(8*(h)+2, PKW(lsg,2), SHF2(L1,0)) \
            GEL1(8*(h)+3, PKW(lsg,3), SHF2(L1,1)) \
            GEL1(8*(h)+4, PKW(lsg,4), SHF2(L2,0)) \
            GEL1(8*(h)+5, PKW(lsg,5), SHF2(L2,1)) \
            GEL1(8*(h)+6, PKW(lsg,6), SHF2(L3,0)) \
            GEL1(8*(h)+7, PKW(lsg,7), SHF2(L3,1)) }
            GELH(0, aln0) GELH(1, aln1) GELH(2, aln2) GELH(3, aln3)
        }

        // ---- out matmul PACKED (r12-verbatim): u[i] = sum_p xe2[p]*owT[i].pair(p) ----
        float u[SD];
#define OUTI(i) { f16s wa, wb, wc, wd; \
        SLOAD4(wa, wb, wc, wd, owt, (i)*256, (i)*256+64, (i)*256+128, (i)*256+192) \
        f2 acc = {0.f, 0.f}; \
        AP8(OPK_E, acc, 0,  wa) AP8(OPK_E, acc, 8,  wb) \
        AP8(OPK_E, acc, 16, wc) AP8(OPK_E, acc, 24, wd) \
        u[i] = (acc.x + acc.y) + obv[i]; }
        REP7(OUTI)

        // ---- L2 normalize (identical) ----
        float ss = 0.f;
#define SSQ(i) ss = fmaf(u[i], u[i], ss);
        REP7(SSQ)
        float inv = __fdividef(1.0f, sqrtf(ss) + 1e-8f);

        // ---- damped update + convergence (identical) ----
        float dd = 0.f;
#define UPD(i) { float un = u[i] * inv; float mn = 0.5f * mu[i] + 0.5f * un; \
        float d = mn - mu[i]; dd = fmaf(d, d, dd); mu[i] = mn; }
        REP7(UPD)
        if (sqrtf(dd) < 1e-4f) conv = 1.0f;
    }

#define ST(i) out_mu[(size_t)row * SD + (i)] = mu[i];
    REP7(ST)
    out_cv[row] = conv;
}

extern "C" void kernel_launch(void* const* d_in, const int* in_sizes, int n_in,
                              void* d_out, int out_size, void* d_ws, size_t ws_size,
                              hipStream_t stream) {
    const float* s7  = (const float*)d_in[0];
    const float* w0  = (const float*)d_in[1];
    const float* b0  = (const float*)d_in[2];
    const float* lns = (const float*)d_in[3];
    const float* lnb = (const float*)d_in[4];
    const float* ow  = (const float*)d_in[5];
    const float* ob  = (const float*)d_in[6];
    const int Bn = in_sizes[0] / SD;

    float* out_mu = (float*)d_out;
    float* out_cv = out_mu + (size_t)Bn * SD;
    float* owt    = (float*)d_ws;            // 448 floats = 1792 B scratch

    hipLaunchKernelGGL(transpose_ow_kernel, dim3(1), dim3(512), 0, stream, ow, owt);

    const int block = 256;
    const int grid  = (Bn + block - 1) / block;
    hipLaunchKernelGGL(strange_loop_kernel, dim3(grid), dim3(block), 0, stream,
                       s7, w0, b0, lns, lnb, owt, ob, out_mu, out_cv, Bn);
}